// Round 2
// baseline (1263.164 us; speedup 1.0000x reference)
//
#include <hip/hip_runtime.h>

#define NNODES 100000
#define NEDGES 1600000
#define NGRAPH 512
#define EPSBN 1e-5f

typedef unsigned short ushort_t;
typedef unsigned int uint_t;

typedef __attribute__((ext_vector_type(8))) __bf16 bf16x8;
typedef __attribute__((ext_vector_type(4))) float f32x4;

__device__ __forceinline__ float b2f(ushort_t u){ return __uint_as_float(((uint_t)u)<<16); }
__device__ __forceinline__ ushort_t f2b(float f){
  uint_t x = __float_as_uint(f);
  uint_t r = (x + 0x7fffu + ((x>>16)&1u))>>16;
  return (ushort_t)r;
}
__device__ __forceinline__ float lo16(uint_t d){ return b2f((ushort_t)(d & 0xffffu)); }
__device__ __forceinline__ float hi16(uint_t d){ return b2f((ushort_t)(d >> 16)); }

__device__ __forceinline__ f32x4 mfma_bf16(bf16x8 a, bf16x8 b, f32x4 c){
  return __builtin_amdgcn_mfma_f32_16x16x32_bf16(a, b, c, 0, 0, 0);
}

union Frag8 { ushort_t u[8]; bf16x8 v; };

__device__ __forceinline__ bf16x8 cvt8_f32_bf16(const float* __restrict__ p){
  Frag8 f;
  #pragma unroll
  for (int i = 0; i < 8; ++i) f.u[i] = f2b(p[i]);
  return f.v;
}

// ---------------- preprocessing ----------------

__global__ void k_deg(const int* __restrict__ dst, int* __restrict__ degcnt){
  int e = blockIdx.x*256 + threadIdx.x;
  if (e < NEDGES) atomicAdd(&degcnt[dst[e]], 1);
}

__global__ void k_ncnt(const int* __restrict__ batch, int* __restrict__ ncnt){
  int v = blockIdx.x*256 + threadIdx.x;
  if (v < NNODES) atomicAdd(&ncnt[batch[v]], 1);
}

__global__ void k_dinv(const int* __restrict__ degcnt, float* __restrict__ dinv){
  int v = blockIdx.x*256 + threadIdx.x;
  if (v < NNODES) dinv[v] = rsqrtf((float)(degcnt[v] + 1));
}

__global__ void k_scanA(const int* __restrict__ degcnt, int* __restrict__ blocksum){
  __shared__ int red[256];
  int base = blockIdx.x*1024;
  int s = 0;
  #pragma unroll
  for (int k = 0; k < 4; ++k){
    int idx = base + k*256 + threadIdx.x;
    s += (idx < NNODES) ? degcnt[idx] : 0;
  }
  red[threadIdx.x] = s; __syncthreads();
  for (int off = 128; off > 0; off >>= 1){
    if ((int)threadIdx.x < off) red[threadIdx.x] += red[threadIdx.x + off];
    __syncthreads();
  }
  if (threadIdx.x == 0) blocksum[blockIdx.x] = red[0];
}

__global__ void k_scanB(const int* __restrict__ blocksum, int* __restrict__ blockoff,
                        int* __restrict__ rowptr, int nblocks){
  __shared__ int s[128];
  int t = threadIdx.x;
  int v = (t < nblocks) ? blocksum[t] : 0;
  s[t] = v; __syncthreads();
  for (int off = 1; off < 128; off <<= 1){
    int add = (t >= off) ? s[t - off] : 0;
    __syncthreads();
    s[t] += add;
    __syncthreads();
  }
  if (t < nblocks) blockoff[t] = s[t] - v;
  if (t == 127) rowptr[NNODES] = s[127];
}

__global__ void k_scanC(const int* __restrict__ degcnt, const int* __restrict__ blockoff,
                        int* __restrict__ rowptr, int* __restrict__ wptr){
  __shared__ int s[256];
  int t = threadIdx.x;
  int base = blockIdx.x*1024 + t*4;
  int v0 = (base + 0 < NNODES) ? degcnt[base + 0] : 0;
  int v1 = (base + 1 < NNODES) ? degcnt[base + 1] : 0;
  int v2 = (base + 2 < NNODES) ? degcnt[base + 2] : 0;
  int v3 = (base + 3 < NNODES) ? degcnt[base + 3] : 0;
  int tot = v0 + v1 + v2 + v3;
  s[t] = tot; __syncthreads();
  for (int off = 1; off < 256; off <<= 1){
    int add = (t >= off) ? s[t - off] : 0;
    __syncthreads();
    s[t] += add;
    __syncthreads();
  }
  int pre = s[t] - tot + blockoff[blockIdx.x];
  int p0 = pre, p1 = pre + v0, p2 = pre + v0 + v1, p3 = pre + v0 + v1 + v2;
  if (base + 0 < NNODES){ rowptr[base + 0] = p0; wptr[base + 0] = p0; }
  if (base + 1 < NNODES){ rowptr[base + 1] = p1; wptr[base + 1] = p1; }
  if (base + 2 < NNODES){ rowptr[base + 2] = p2; wptr[base + 2] = p2; }
  if (base + 3 < NNODES){ rowptr[base + 3] = p3; wptr[base + 3] = p3; }
}

__global__ void k_fill(const int* __restrict__ src, const int* __restrict__ dst,
                       int* __restrict__ wptr, int* __restrict__ colx){
  int e = blockIdx.x*256 + threadIdx.x;
  if (e < NEDGES){
    int pos = atomicAdd(&wptr[dst[e]], 1);
    colx[pos] = src[e];
  }
}

// ---------------- per-layer kernels ----------------

// WT[j*136 + c] = bf16(W0[c*128 + j])  (plain transpose, layer 0; W fp32)
__global__ void k_transpose(const float* __restrict__ W, ushort_t* __restrict__ WT){
  int j = blockIdx.x, c = threadIdx.x;
  WT[j*136 + c] = f2b(W[c*128 + j]);
}

// GEMM: hs[m][n] = bf16( ( sum_k A[m][k]*WT[n][k] + K[n] ) * dinv[m] )
// A is fp32 (layer 0) or bf16 (layers 1,2); WT bf16 in LDS; out bf16.
template<bool AF32>
__global__ __launch_bounds__(256) void k_gemm(const void* __restrict__ Av,
                                              const ushort_t* __restrict__ WT,
                                              const float* __restrict__ Kv,
                                              const float* __restrict__ dinv,
                                              ushort_t* __restrict__ hs){
  __shared__ __attribute__((aligned(16))) ushort_t sWT[128*136];
  {
    const uint4* sp = (const uint4*)WT;
    uint4* dp = (uint4*)sWT;
    for (int i = threadIdx.x; i < (128*136*2)/16; i += 256) dp[i] = sp[i];
  }
  __syncthreads();

  int wave = threadIdx.x >> 6;
  int lane = threadIdx.x & 63;
  int quad = lane >> 4;
  int l16  = lane & 15;
  int row0 = blockIdx.x*64 + wave*16;

  int m  = row0 + l16;
  int mc = (m < NNODES) ? m : (NNODES - 1);

  bf16x8 af0, af1, af2, af3;
  if constexpr (AF32){
    const float* ap = (const float*)Av + (size_t)mc*128 + quad*8;
    af0 = cvt8_f32_bf16(ap);
    af1 = cvt8_f32_bf16(ap + 32);
    af2 = cvt8_f32_bf16(ap + 64);
    af3 = cvt8_f32_bf16(ap + 96);
  } else {
    const ushort_t* ap = (const ushort_t*)Av + (size_t)mc*128 + quad*8;
    af0 = *(const bf16x8*)(const void*)(ap);
    af1 = *(const bf16x8*)(const void*)(ap + 32);
    af2 = *(const bf16x8*)(const void*)(ap + 64);
    af3 = *(const bf16x8*)(const void*)(ap + 96);
  }

  f32x4 acc[8];
  #pragma unroll
  for (int ct = 0; ct < 8; ++ct){
    const ushort_t* bp = sWT + (ct*16 + l16)*136 + quad*8;
    bf16x8 b0 = *(const bf16x8*)(const void*)(bp);
    bf16x8 b1 = *(const bf16x8*)(const void*)(bp + 32);
    bf16x8 b2 = *(const bf16x8*)(const void*)(bp + 64);
    bf16x8 b3 = *(const bf16x8*)(const void*)(bp + 96);
    f32x4 a_ = {0.f, 0.f, 0.f, 0.f};
    a_ = mfma_bf16(af0, b0, a_);
    a_ = mfma_bf16(af1, b1, a_);
    a_ = mfma_bf16(af2, b2, a_);
    a_ = mfma_bf16(af3, b3, a_);
    acc[ct] = a_;
  }

  int rbase = row0 + quad*4;
  float dv[4];
  #pragma unroll
  for (int rg = 0; rg < 4; ++rg){
    int rr = rbase + rg;
    dv[rg] = dinv[(rr < NNODES) ? rr : (NNODES - 1)];
  }
  #pragma unroll
  for (int ct = 0; ct < 8; ++ct){
    int colc = ct*16 + l16;
    float kv = Kv[colc];
    #pragma unroll
    for (int rg = 0; rg < 4; ++rg){
      int rr = rbase + rg;
      if (rr < NNODES){
        float val = (acc[ct][rg] + kv) * dv[rg];
        hs[(size_t)rr*128 + colc] = f2b(val);
      }
    }
  }
}

// Aggregation: r[v] = relu(dinv[v]*(hs[v] + sum_in hs[u]) + b); accumulate pool sums (batch
// sorted -> register-run accumulation) and per-channel sum/sumsq for BN.
#define AGG_BLOCKS 1024
#define AGG_WAVES (AGG_BLOCKS*4)
#define AGG_CHUNK ((NNODES + AGG_WAVES - 1) / AGG_WAVES)

__global__ __launch_bounds__(256) void k_agg(const ushort_t* __restrict__ hs,
                                             const int* __restrict__ rowptr,
                                             const int* __restrict__ colx,
                                             const float* __restrict__ dinv,
                                             const float* __restrict__ bias,
                                             const int* __restrict__ batch,
                                             ushort_t* __restrict__ rout,
                                             float* __restrict__ poolS,
                                             float* __restrict__ chansum,
                                             float* __restrict__ chansumsq){
  int wave = __builtin_amdgcn_readfirstlane((blockIdx.x << 2) + (threadIdx.x >> 6));
  int lane = threadIdx.x & 63;
  int n0 = wave * AGG_CHUNK;
  int n1 = (n0 + AGG_CHUNK < NNODES) ? (n0 + AGG_CHUNK) : NNODES;

  const uint_t* H = (const uint_t*)hs;
  uint_t* R = (uint_t*)rout;

  float bb0 = bias[lane*2];
  float bb1 = bias[lane*2 + 1];

  float ss0 = 0.f, ss1 = 0.f, sq0 = 0.f, sq1 = 0.f;
  float p0 = 0.f, p1 = 0.f;
  int curg = -1;

  for (int v = n0; v < n1; ++v){
    int g = batch[v];
    if (g != curg){
      if (curg >= 0){
        atomicAdd(&poolS[curg*128 + lane*2],     p0);
        atomicAdd(&poolS[curg*128 + lane*2 + 1], p1);
      }
      p0 = 0.f; p1 = 0.f; curg = g;
    }
    int rs = rowptr[v], re = rowptr[v + 1];
    uint_t dself = H[(size_t)v*64 + lane];
    float a0 = lo16(dself), a1 = hi16(dself);
    int e = rs;
    for (; e + 3 < re; e += 4){
      int u0 = colx[e], u1 = colx[e+1], u2 = colx[e+2], u3 = colx[e+3];
      uint_t d0 = H[(size_t)u0*64 + lane];
      uint_t d1 = H[(size_t)u1*64 + lane];
      uint_t d2 = H[(size_t)u2*64 + lane];
      uint_t d3 = H[(size_t)u3*64 + lane];
      a0 += lo16(d0) + lo16(d1) + lo16(d2) + lo16(d3);
      a1 += hi16(d0) + hi16(d1) + hi16(d2) + hi16(d3);
    }
    for (; e < re; ++e){
      int u = colx[e];
      uint_t d = H[(size_t)u*64 + lane];
      a0 += lo16(d);
      a1 += hi16(d);
    }
    float dvv = dinv[v];
    a0 = fmaxf(a0*dvv + bb0, 0.f);
    a1 = fmaxf(a1*dvv + bb1, 0.f);
    R[(size_t)v*64 + lane] = (uint_t)f2b(a0) | ((uint_t)f2b(a1) << 16);
    ss0 += a0; ss1 += a1;
    sq0 += a0*a0; sq1 += a1*a1;
    p0 += a0; p1 += a1;
  }
  if (curg >= 0){
    atomicAdd(&poolS[curg*128 + lane*2],     p0);
    atomicAdd(&poolS[curg*128 + lane*2 + 1], p1);
  }
  atomicAdd(&chansum[lane*2],     ss0);
  atomicAdd(&chansum[lane*2 + 1], ss1);
  atomicAdd(&chansumsq[lane*2],     sq0);
  atomicAdd(&chansumsq[lane*2 + 1], sq1);
}

// BN affine coefficients: a = gamma*rstd ; c = beta - mu*a   (gamma/beta fp32)
__global__ void k_bnstats(const float* __restrict__ chansum, const float* __restrict__ chansumsq,
                          const float* __restrict__ gamma, const float* __restrict__ beta,
                          float* __restrict__ avec, float* __restrict__ cvec){
  int c = threadIdx.x;
  const float invN = 1.0f / (float)NNODES;
  float mu  = chansum[c] * invN;
  float var = chansumsq[c] * invN - mu*mu;
  float rstd = rsqrtf(var + EPSBN);
  float a = gamma[c] * rstd;
  avec[c] = a;
  cvec[c] = beta[c] - mu*a;
}

// Fold BN into next layer's weights: WT[j][c] = bf16(a_c*W[c][j]), K[j] = sum_c c_c*W[c][j]
__global__ void k_fold(const float* __restrict__ Wn, const float* __restrict__ avec,
                       const float* __restrict__ cvec, ushort_t* __restrict__ WT,
                       float* __restrict__ Kv){
  __shared__ float red[128];
  int j = blockIdx.x, c = threadIdx.x;
  float wv = Wn[c*128 + j];
  WT[j*136 + c] = f2b(avec[c] * wv);
  red[c] = cvec[c] * wv;
  __syncthreads();
  for (int off = 64; off > 0; off >>= 1){
    if (c < off) red[c] += red[c + off];
    __syncthreads();
  }
  if (c == 0) Kv[j] = red[0];
}

// out[g][i*128+c] = a_i[c]*S_i[g][c] + n_g*c_i[c]   (fp32 out)
__global__ void k_final(const float* __restrict__ poolS, const int* __restrict__ ncnt,
                        const float* __restrict__ avec, const float* __restrict__ cvec,
                        float* __restrict__ out){
  int g = blockIdx.x, c = threadIdx.x;
  float n = (float)ncnt[g];
  #pragma unroll
  for (int i = 0; i < 3; ++i){
    float v = avec[i*128 + c] * poolS[((size_t)i*NGRAPH + g)*128 + c] + n * cvec[i*128 + c];
    out[(size_t)g*384 + i*128 + c] = v;
  }
}

extern "C" void kernel_launch(void* const* d_in, const int* in_sizes, int n_in,
                              void* d_out, int out_size, void* d_ws, size_t ws_size,
                              hipStream_t stream){
  (void)in_sizes; (void)n_in; (void)out_size; (void)ws_size;

  const float* x     = (const float*)d_in[0];
  const int*   ei    = (const int*)d_in[1];
  const int*   batch = (const int*)d_in[2];
  const float* Wp[3] = {(const float*)d_in[3], (const float*)d_in[7],  (const float*)d_in[11]};
  const float* bp[3] = {(const float*)d_in[4], (const float*)d_in[8],  (const float*)d_in[12]};
  const float* gp[3] = {(const float*)d_in[5], (const float*)d_in[9],  (const float*)d_in[13]};
  const float* tp[3] = {(const float*)d_in[6], (const float*)d_in[10], (const float*)d_in[14]};
  const int* srcp = ei;
  const int* dstp = ei + NEDGES;

  char* w = (char*)d_ws;
  size_t off = 0;
  auto take = [&](size_t bytes) -> char* {
    char* p = w + off;
    off += (bytes + 511) & ~(size_t)511;
    return p;
  };
  int*      degcnt    = (int*)take((size_t)NNODES*4);
  int*      rowptr    = (int*)take((size_t)(NNODES+1)*4);
  int*      wptr      = (int*)take((size_t)NNODES*4);
  int*      colx      = (int*)take((size_t)NEDGES*4);
  float*    dinv      = (float*)take((size_t)NNODES*4);
  int*      blocksum  = (int*)take(128*4);
  int*      blockoff  = (int*)take(128*4);
  ushort_t* hs        = (ushort_t*)take((size_t)NNODES*128*2);
  ushort_t* rbuf      = (ushort_t*)take((size_t)NNODES*128*2);
  ushort_t* WT        = (ushort_t*)take(128*136*2);
  float*    Kv        = (float*)take(128*4);
  float*    chanstats = (float*)take(3*256*4);
  float*    poolS     = (float*)take((size_t)3*NGRAPH*128*4);
  int*      ncnt      = (int*)take(NGRAPH*4);
  float*    avec      = (float*)take(3*128*4);
  float*    cvec      = (float*)take(3*128*4);

  hipMemsetAsync(degcnt,    0, (size_t)NNODES*4,         stream);
  hipMemsetAsync(ncnt,      0, NGRAPH*4,                 stream);
  hipMemsetAsync(poolS,     0, (size_t)3*NGRAPH*128*4,   stream);
  hipMemsetAsync(chanstats, 0, 3*256*4,                  stream);
  hipMemsetAsync(Kv,        0, 128*4,                    stream);

  const int EG = (NEDGES + 255)/256;
  const int NG = (NNODES + 255)/256;
  const int SB = (NNODES + 1023)/1024;   // 98 scan blocks

  k_deg <<<EG, 256, 0, stream>>>(dstp, degcnt);
  k_ncnt<<<NG, 256, 0, stream>>>(batch, ncnt);
  k_dinv<<<NG, 256, 0, stream>>>(degcnt, dinv);
  k_scanA<<<SB, 256, 0, stream>>>(degcnt, blocksum);
  k_scanB<<<1, 128, 0, stream>>>(blocksum, blockoff, rowptr, SB);
  k_scanC<<<SB, 256, 0, stream>>>(degcnt, blockoff, rowptr, wptr);
  k_fill<<<EG, 256, 0, stream>>>(srcp, dstp, wptr, colx);
  k_transpose<<<128, 128, 0, stream>>>(Wp[0], WT);

  const int gemmGrid = (NNODES + 63)/64;
  for (int i = 0; i < 3; ++i){
    if (i == 0)
      k_gemm<true><<<gemmGrid, 256, 0, stream>>>((const void*)x, WT, Kv, dinv, hs);
    else
      k_gemm<false><<<gemmGrid, 256, 0, stream>>>((const void*)rbuf, WT, Kv, dinv, hs);
    k_agg<<<AGG_BLOCKS, 256, 0, stream>>>(hs, rowptr, colx, dinv, bp[i], batch, rbuf,
                                          poolS + (size_t)i*NGRAPH*128,
                                          chanstats + i*256, chanstats + i*256 + 128);
    k_bnstats<<<1, 128, 0, stream>>>(chanstats + i*256, chanstats + i*256 + 128,
                                     gp[i], tp[i], avec + i*128, cvec + i*128);
    if (i < 2)
      k_fold<<<128, 128, 0, stream>>>(Wp[i+1], avec + i*128, cvec + i*128, WT, Kv);
  }
  k_final<<<NGRAPH, 128, 0, stream>>>(poolS, ncnt, avec, cvec, (float*)d_out);
}